// Round 12
// baseline (4582.438 us; speedup 1.0000x reference)
//
#include <hip/hip_runtime.h>

// LSTM char-RNN scan: B=512, SEQ=1024, UNITS=256, NUM_CHARS=128. fp32 in/out.
// Round 11 = r11 winner (4.52 ms: 16 waves, 2REG/1LDS/1STREAM nt per wave,
// bf16 h, 2-barrier step) + latency-exposure fixes, numerics frozen:
//   1. token+Wxp gathers hoisted ABOVE the MFMA phase (loads overlap MFMA,
//      consumed in update) — was ~300-400 cyc naked at update start.
//   2. stream tile kt=0 resident in 4 VGPRs (address is step-invariant);
//      kills the post-barrier L2 exposure on the first stream use.
//   3. explicit 3-deep stream pipeline (tiles 1,2 pre-issued; tile kt+3
//      issued at kt) — was 1-deep (~60 cyc cover vs ~300 cyc L2 latency).
// Risk: +~28 arch regs; if occupancy drops 4->3 waves/SIMD, revert #1.

#define U       256
#define SEQ     1024
#define NC      128
#define GDIM    1024
#define BCR     16         // batch rows per WG
#define THREADS 1024       // 16 waves

typedef short bf16x8 __attribute__((ext_vector_type(8)));
typedef float f32x4  __attribute__((ext_vector_type(4)));

#define WP_OFF   0                        // 512 KB packed W_h
#define WXP_OFF  (512*1024)               // 512 KB packed Wx+bias
#define WS_NEED  (1024*1024)

__device__ __forceinline__ float sig_(float x)  { return 1.0f / (1.0f + __expf(-x)); }
__device__ __forceinline__ float tanh_(float x) { return 1.0f - 2.0f / (__expf(2.0f * x) + 1.0f); }
__device__ __forceinline__ unsigned rne16(float f) {
    union { float f; unsigned u; } v; v.f = f;
    return (v.u + 0x7FFFu + ((v.u >> 16) & 1u)) >> 16;
}
__device__ __forceinline__ float u2f(unsigned u) {
    union { unsigned u; float f; } v; v.u = u; return v.f;
}

// ---- pack W_h into MFMA B-frag order (validated rounds 5-11) ----
// Wp[(nt*8+kt)*64 + lane]: col = nt*16+(lane&15); k = kt*32+(lane>>4)*8 + j,
// dword d packs (k=2d lo, k=2d+1 hi).
__global__ __launch_bounds__(256)
void pack_wh(const float* __restrict__ Wh, uint4* __restrict__ Wp) {
    int i    = blockIdx.x * 256 + threadIdx.x;   // [0, 32768)
    int lane = i & 63;
    int kt   = (i >> 6) & 7;
    int nt   = i >> 9;
    int col  = nt * 16 + (lane & 15);
    int k0   = kt * 32 + ((lane >> 4) * 8);
    const float* base = Wh + (size_t)k0 * GDIM + col;
    unsigned p0 = rne16(base[0 * GDIM]) | (rne16(base[1 * GDIM]) << 16);
    unsigned p1 = rne16(base[2 * GDIM]) | (rne16(base[3 * GDIM]) << 16);
    unsigned p2 = rne16(base[4 * GDIM]) | (rne16(base[5 * GDIM]) << 16);
    unsigned p3 = rne16(base[6 * GDIM]) | (rne16(base[7 * GDIM]) << 16);
    Wp[i] = make_uint4(p0, p1, p2, p3);
}

// ---- pack Wx + bias (+forget_bias) into float4 per (x, unit) ----
__global__ __launch_bounds__(256)
void pack_wx(const float* __restrict__ Wx, const float* __restrict__ bias,
             float4* __restrict__ Wxp) {
    int i = blockIdx.x * 256 + threadIdx.x;      // [0, 32768)
    int x = i >> 8, u = i & 255;
    const float* r = Wx + (size_t)x * GDIM;
    Wxp[i] = make_float4(r[u]       + bias[u],
                         r[256 + u] + bias[256 + u],
                         r[512 + u] + bias[512 + u] + 1.0f,   // forget_bias
                         r[768 + u] + bias[768 + u]);
}

__global__ __launch_bounds__(THREADS, 4)
void lstm_reg16(const int* __restrict__ tokens,
                const uint4* __restrict__ Wp,     // packed W_h (ws)
                const float4* __restrict__ Wxp,   // packed Wx+b (ws)
                const float* __restrict__ Wd,     // [256,128]
                const float* __restrict__ bd,     // [128]
                float* __restrict__ out)          // [512,128]
{
    __shared__ uint4 LW[16][8][64];   // 128 KB  W in LDS (1 nt per wave)
    __shared__ short AH[8][64][8];    // 8 KB    h bf16, MFMA-A swizzled
    __shared__ int   tokw[64][16];    // 4 KB    64-step token window

    const int tid  = threadIdx.x;
    const int wv   = tid >> 6;        // wave 0..15
    const int lane = tid & 63;
    const int m    = lane & 15;
    const int quad = lane >> 4;
    const int r0   = blockIdx.x * BCR;

    // wave wv owns unit block wv (units wv*16+m); gates i,j,f,o at
    // nt = wv, 16+wv, 32+wv, 48+wv.  REG: {wv, 16+wv}. LDS: {32+wv}.
    // STREAM: {48+wv} (kt=0 tile resident, kt=1..7 pipelined 3-deep).
    bf16x8 WR[2][8];                  // 64 regs
    #pragma unroll
    for (int jj = 0; jj < 2; ++jj)
        #pragma unroll
        for (int kt = 0; kt < 8; ++kt) {
            union { uint4 u; bf16x8 v; } c;
            c.u = Wp[((size_t)((wv + 16 * jj) * 8 + kt)) * 64 + lane];
            WR[jj][kt] = c.v;
        }
    #pragma unroll
    for (int kt = 0; kt < 8; ++kt)
        LW[wv][kt][lane] = Wp[((size_t)((32 + wv) * 8 + kt)) * 64 + lane];
    for (int i = tid; i < 2048; i += THREADS)    // zero A plane (as ints)
        ((int*)AH)[i] = 0;

    float cst[4] = {0.f, 0.f, 0.f, 0.f};
    const int uA = wv * 16 + m;
    const int kt_u = uA >> 5, qa = (uA >> 3) & 3, ju = uA & 7;
    const uint4* sp = Wp + ((size_t)(48 + wv) * 8) * 64 + lane;
    const uint4 sres0 = sp[0];        // kt=0 stream tile: resident forever

    __syncthreads();

    for (int t = 0; t < SEQ; ++t) {
        if ((t & 63) == 0) {           // refresh token window
            tokw[tid >> 4][tid & 15] =
                tokens[(size_t)(r0 + (tid & 15)) * SEQ + t + (tid >> 4)];
            __syncthreads();
        }

        // ---- hoisted gathers: consumed after the MFMA phase ----
        int xs[4];
        #pragma unroll
        for (int ri = 0; ri < 4; ++ri)
            xs[ri] = tokw[t & 63][quad * 4 + ri];
        float4 wx[4];
        #pragma unroll
        for (int ri = 0; ri < 4; ++ri)
            wx[ri] = Wxp[(size_t)xs[ri] * 256 + uA];

        // ---- MFMA phase: 4 acc x 8 kt, 3-deep stream pipeline ----
        f32x4 acc[4];
        #pragma unroll
        for (int j = 0; j < 4; ++j) acc[j] = (f32x4){0.f, 0.f, 0.f, 0.f};

        uint4 s1 = sp[1 * 64], s2 = sp[2 * 64];
        uint4 s3, s4, s5, s6, s7;

#define STEPK(KT, BSRC, PRE)                                                   \
        {                                                                      \
            bf16x8 ah = *(const bf16x8*)&AH[KT][lane][0];                      \
            PRE;                                                               \
            union { uint4 u; bf16x8 v; } l, b;                                 \
            l.u = LW[wv][KT][lane];                                            \
            b.u = BSRC;                                                        \
            acc[0] = __builtin_amdgcn_mfma_f32_16x16x32_bf16(ah, WR[0][KT], acc[0], 0, 0, 0); \
            acc[1] = __builtin_amdgcn_mfma_f32_16x16x32_bf16(ah, WR[1][KT], acc[1], 0, 0, 0); \
            acc[2] = __builtin_amdgcn_mfma_f32_16x16x32_bf16(ah, l.v, acc[2], 0, 0, 0); \
            acc[3] = __builtin_amdgcn_mfma_f32_16x16x32_bf16(ah, b.v, acc[3], 0, 0, 0); \
        }
        STEPK(0, sres0, s3 = sp[3 * 64])
        STEPK(1, s1,    s4 = sp[4 * 64])
        STEPK(2, s2,    s5 = sp[5 * 64])
        STEPK(3, s3,    s6 = sp[6 * 64])
        STEPK(4, s4,    s7 = sp[7 * 64])
        STEPK(5, s5, )
        STEPK(6, s6, )
        STEPK(7, s7, )
#undef STEPK

        // ---- in-register LSTM update (4 rows per lane, 1 unit) ----
        unsigned hh[4];
        #pragma unroll
        for (int ri = 0; ri < 4; ++ri) {
            float gi = acc[0][ri] + wx[ri].x;
            float gj = acc[1][ri] + wx[ri].y;
            float gf = acc[2][ri] + wx[ri].z;    // forget_bias folded
            float go = acc[3][ri] + wx[ri].w;
            float c  = cst[ri];
            c = c * sig_(gf) + sig_(gi) * tanh_(gj);
            cst[ri] = c;
            hh[ri] = rne16(tanh_(c) * sig_(go));
        }
        __syncthreads();       // all A-reads of this step complete

        #pragma unroll
        for (int ri = 0; ri < 4; ++ri)
            AH[kt_u][qa * 16 + quad * 4 + ri][ju] = (short)hh[ri];
        __syncthreads();       // new h visible
    }

    // ---- final dense (h is bf16) ----
    for (int o = tid; o < BCR * NC; o += THREADS) {
        const int r = o >> 7;
        const int n = o & (NC - 1);
        float sum = bd[n];
        #pragma unroll 4
        for (int k = 0; k < U; ++k) {
            float hk = u2f(((unsigned)(unsigned short)
                            AH[k >> 5][((k >> 3) & 3) * 16 + r][k & 7]) << 16);
            sum = fmaf(hk, Wd[k * NC + n], sum);
        }
        out[(size_t)(r0 + r) * NC + n] = sum;
    }
}

// ================= fallback: round-5 streaming kernel (proven 7.6 ms) =========
__global__ __launch_bounds__(256)
void pack_kq(const float* __restrict__ Wh, uint4* __restrict__ Whb) {
    int idx = blockIdx.x * 256 + threadIdx.x;
    int kq  = idx >> 10;
    int c   = idx & 1023;
    const float* base = Wh + (size_t)(kq * 8) * GDIM + c;
    unsigned p0 = rne16(base[0 * GDIM]) | (rne16(base[1 * GDIM]) << 16);
    unsigned p1 = rne16(base[2 * GDIM]) | (rne16(base[3 * GDIM]) << 16);
    unsigned p2 = rne16(base[4 * GDIM]) | (rne16(base[5 * GDIM]) << 16);
    unsigned p3 = rne16(base[6 * GDIM]) | (rne16(base[7 * GDIM]) << 16);
    Whb[idx] = make_uint4(p0, p1, p2, p3);
}

__global__ __launch_bounds__(1024, 4)
void lstm_stream(const int* __restrict__ tokens, const float* __restrict__ Wx,
                 const uint4* __restrict__ Whb, const float* __restrict__ bias,
                 const float* __restrict__ Wd, const float* __restrict__ bd,
                 float* __restrict__ out)
{
    __shared__ float h32[2][U];
    __shared__ float G2[GDIM][2];
    __shared__ int   tok[2][SEQ];
    const int tid = threadIdx.x;
    const int r0  = blockIdx.x * 2;
    for (int i = tid; i < 2 * SEQ; i += 1024)
        ((int*)tok)[i] = tokens[r0 * SEQ + i];
    if (tid < 2 * U) ((float*)h32)[tid] = 0.0f;
    const float b_c = bias[tid];
    float c_state = 0.0f;
    const int ur = tid >> 8, uu = tid & 255;
    __syncthreads();
    const uint4* wp = Whb + tid;
    for (int t = 0; t < SEQ; ++t) {
        const int x0 = tok[0][t], x1 = tok[1][t];
        float a0e = Wx[x0 * GDIM + tid] + b_c;
        float a1e = Wx[x1 * GDIM + tid] + b_c;
        float a0o = 0.f, a1o = 0.f;
        #pragma unroll 4
        for (int kq = 0; kq < 32; ++kq) {
            float4 h0a = *(const float4*)&h32[0][kq * 8];
            float4 h0b = *(const float4*)&h32[0][kq * 8 + 4];
            float4 h1a = *(const float4*)&h32[1][kq * 8];
            float4 h1b = *(const float4*)&h32[1][kq * 8 + 4];
            uint4 wv2 = wp[kq << 10];
            float we0 = u2f(wv2.x << 16), wo0 = u2f(wv2.x & 0xffff0000u);
            float we1 = u2f(wv2.y << 16), wo1 = u2f(wv2.y & 0xffff0000u);
            float we2 = u2f(wv2.z << 16), wo2 = u2f(wv2.z & 0xffff0000u);
            float we3 = u2f(wv2.w << 16), wo3 = u2f(wv2.w & 0xffff0000u);
            a0e = fmaf(h0a.x, we0, a0e); a0o = fmaf(h0a.y, wo0, a0o);
            a1e = fmaf(h1a.x, we0, a1e); a1o = fmaf(h1a.y, wo0, a1o);
            a0e = fmaf(h0a.z, we1, a0e); a0o = fmaf(h0a.w, wo1, a0o);
            a1e = fmaf(h1a.z, we1, a1e); a1o = fmaf(h1a.w, wo1, a1o);
            a0e = fmaf(h0b.x, we2, a0e); a0o = fmaf(h0b.y, wo2, a0o);
            a1e = fmaf(h1b.x, we2, a1e); a1o = fmaf(h1b.y, wo2, a1o);
            a0e = fmaf(h0b.z, we3, a0e); a0o = fmaf(h0b.w, wo3, a0o);
            a1e = fmaf(h1b.z, we3, a1e); a1o = fmaf(h1b.w, wo3, a1o);
        }
        *(float2*)&G2[tid][0] = make_float2(a0e + a0o, a1e + a1o);
        __syncthreads();
        if (tid < 2 * U) {
            float gi = G2[uu][ur], gj = G2[U + uu][ur];
            float gf = G2[2 * U + uu][ur], go = G2[3 * U + uu][ur];
            c_state = c_state * sig_(gf + 1.0f) + sig_(gi) * tanh_(gj);
            h32[ur][uu] = tanh_(c_state) * sig_(go);
        }
        __syncthreads();
    }
    if (tid < 2 * NC) {
        const int r = tid >> 7, n = tid & (NC - 1);
        float sum = bd[n];
        #pragma unroll 4
        for (int k = 0; k < U; ++k)
            sum = fmaf(h32[r][k], Wd[k * NC + n], sum);
        out[(r0 + r) * NC + n] = sum;
    }
}

extern "C" void kernel_launch(void* const* d_in, const int* in_sizes, int n_in,
                              void* d_out, int out_size, void* d_ws, size_t ws_size,
                              hipStream_t stream) {
    const int*   tokens = (const int*)d_in[0];
    const float* Wx     = (const float*)d_in[1];
    const float* Wh     = (const float*)d_in[2];
    const float* bias   = (const float*)d_in[3];
    const float* Wd     = (const float*)d_in[4];
    const float* bd     = (const float*)d_in[5];
    float*       out    = (float*)d_out;

    if (ws_size >= (size_t)WS_NEED) {
        uint4*  Wp  = (uint4*)((char*)d_ws + WP_OFF);
        float4* Wxp = (float4*)((char*)d_ws + WXP_OFF);
        pack_wh<<<128, 256, 0, stream>>>(Wh, Wp);
        pack_wx<<<128, 256, 0, stream>>>(Wx, bias, Wxp);
        lstm_reg16<<<512 / BCR, THREADS, 0, stream>>>(tokens, Wp, Wxp, Wd, bd, out);
    } else {
        uint4* Whb = (uint4*)d_ws;
        pack_kq<<<128, 256, 0, stream>>>(Wh, Whb);
        lstm_stream<<<256, 1024, 0, stream>>>(tokens, Wx, Whb, bias, Wd, bd, out);
    }
}